// Round 14
// baseline (162.373 us; speedup 1.0000x reference)
//
#include <hip/hip_runtime.h>
#include <hip/hip_bf16.h>

#define N 8192
#define D 512

typedef __attribute__((ext_vector_type(4))) float f32x4;
typedef __attribute__((ext_vector_type(2))) long i64x2;

#define WAITVM(n) asm volatile("s_waitcnt vmcnt(" #n ")" ::: "memory")
#define WAITLGKM asm volatile("s_waitcnt lgkmcnt(0)" ::: "memory")

__device__ __forceinline__ void g2l16(const void* g, void* l) {
  __builtin_amdgcn_global_load_lds(
      (const __attribute__((address_space(1))) void*)g,
      (__attribute__((address_space(3))) void*)l, 16, 0, 0);
}

// Prep: f32 -> fp8 e4m3, k-permuted per 64-col group (chunk j = k{8j..8j+7} |
// k{32+8j..8j+7+32}) so one b128 read feeds both K=32 halves of an MFMA pair.
// sq computed from DEQUANTIZED values (diagonal d2 exactly 0).
__global__ __launch_bounds__(128) void prep_kernel(
    const float* __restrict__ X, const float* __restrict__ Y,
    unsigned char* __restrict__ Xb, unsigned char* __restrict__ Yb,
    float* __restrict__ sqX, float* __restrict__ sqY) {
  const int b = blockIdx.x;
  const int row = b & (N - 1);
  const float* src = (b < N) ? X : Y;
  unsigned char* dst = (b < N) ? Xb : Yb;
  float* sq = (b < N) ? sqX : sqY;
  const int t = threadIdx.x;                 // 128 threads x 4 floats = 512
  float4 v = reinterpret_cast<const float4*>(src + (size_t)row * D)[t];
  unsigned p = __builtin_amdgcn_cvt_pk_fp8_f32(v.x, v.y, 0, false);
  p = __builtin_amdgcn_cvt_pk_fp8_f32(v.z, v.w, p, true);
  float f0 = __builtin_amdgcn_cvt_f32_fp8(p, 0);
  float f1 = __builtin_amdgcn_cvt_f32_fp8(p, 1);
  float f2 = __builtin_amdgcn_cvt_f32_fp8(p, 2);
  float f3 = __builtin_amdgcn_cvt_f32_fp8(p, 3);
  float s = f0 * f0 + f1 * f1 + f2 * f2 + f3 * f3;
  const int g = t >> 4;                      // 64-col group
  const int kl = (t & 15) * 4;               // k within group
  const int dest = g * 64 + ((kl & 31) >> 3) * 16 + (kl >> 5) * 8 + (kl & 7);
  *reinterpret_cast<unsigned*>(dst + (size_t)row * D + dest) = p;
  #pragma unroll
  for (int msk = 1; msk < 64; msk <<= 1) s += __shfl_xor(s, msk);
  __shared__ float red[2];
  if ((t & 63) == 0) red[t >> 6] = s;
  __syncthreads();
  if (t == 0) sq[row] = red[0] + red[1];
}

// Fused dual-GEMM (fp8) + RBF + reductions, upper-triangle tiles.
// 3-buffer phase rotation: phase p (X if even, Y if odd; kt=p>>1) consumes
// buffer p%3 while phases p+1,p+2 are in flight -> prefetch lead 2.5 phases.
// vmcnt(16) steady-state (own phase = oldest 8 of 24), peel 16->8->0.
__global__ __launch_bounds__(256, 2) void hsic_main(
    const unsigned char* __restrict__ Xb, const unsigned char* __restrict__ Yb,
    const float* __restrict__ sqX, const float* __restrict__ sqY,
    float* __restrict__ rowK, float* __restrict__ rowL,
    float* __restrict__ sums) {
  __shared__ __align__(16) unsigned char sbuf[3][2][128 * 64];  // 48 KB

  const int bid = (blockIdx.x & 7) * 260 + (blockIdx.x >> 3);  // XCD chunks
  int ti = (int)((129.0f - sqrtf(16641.0f - 8.0f * (float)bid)) * 0.5f);
  while (ti > 0 && (ti * (129 - ti)) / 2 > bid) --ti;
  while (((ti + 1) * (128 - ti)) / 2 <= bid) ++ti;
  const int tj = ti + (bid - (ti * (129 - ti)) / 2);
  const bool diag = (ti == tj);

  const int ib = ti * 128, jb = tj * 128;
  const int t = threadIdx.x;
  const int lane = t & 63, wave = t >> 6;
  const int wr = wave >> 1, wc = wave & 1;     // 2x2 waves, 64x64 tiles
  const int fr = lane & 15, fq = lane >> 4;

  f32x4 accK[4][4], accL[4][4];
  #pragma unroll
  for (int m = 0; m < 4; ++m)
    #pragma unroll
    for (int n = 0; n < 4; ++n) { accK[m][n] = (f32x4)0.f; accL[m][n] = (f32x4)0.f; }

  const unsigned char* s0 = Xb + (size_t)ib * D;
  const unsigned char* s1 = Xb + (size_t)jb * D;
  const unsigned char* s2 = Yb + (size_t)ib * D;
  const unsigned char* s3 = Yb + (size_t)jb * D;

  // Stage: 256 threads x 16B = 4KB = 64 rows x 64B per issue; 2 issues/panel.
  // row = q*64 + t/4, 16B chunk = t&3, XOR-swizzled at 16B granule:
  // swz(row) = ((row>>1)&3)<<4; (row>>1)&3 = (t>>3)&3 (q-independent).
  const int srow = t >> 2;
  const int swcb = ((t & 3) * 16) ^ (((t >> 3) & 3) << 4);
  const int lo16 = t * 16;

  // 8 vmem issues per phase-stage (4 per panel... 2 q x 2 panels).
  auto stage = [&](int phase) {
    const int b = phase % 3;
    const int kt = phase >> 1;
    const unsigned char* si = (phase & 1) ? s2 : s0;
    const unsigned char* sj = (phase & 1) ? s3 : s1;
    #pragma unroll
    for (int q = 0; q < 2; ++q) {
      const size_t goff = (size_t)(q * 64 + srow) * D + kt * 64 + swcb;
      const int lo = q * 4096 + lo16;
      g2l16(si + goff, &sbuf[b][0][lo]);
      g2l16(sj + goff, &sbuf[b][1][lo]);
    }
  };

  // Fragment column (16B chunk fq, swizzled by row: row&7... (row>>1)&3 = (fr>>1)&3).
  const int fcol = (fq * 16) ^ (((fr >> 1) & 3) << 4);

  i64x2 a[4], b[4];
  auto frags = [&](int phase) {
    const int bu = phase % 3;
    const unsigned char* si = sbuf[bu][0];
    const unsigned char* sj = sbuf[bu][1];
    #pragma unroll
    for (int m = 0; m < 4; ++m)
      a[m] = *(const i64x2*)&si[(wr * 64 + m * 16 + fr) * 64 + fcol];
    #pragma unroll
    for (int n = 0; n < 4; ++n)
      b[n] = *(const i64x2*)&sj[(wc * 64 + n * 16 + fr) * 64 + fcol];
  };
  auto mmaInto = [&](f32x4 (&acc)[4][4]) {
    __builtin_amdgcn_s_setprio(1);
    #pragma unroll
    for (int m = 0; m < 4; ++m)
      #pragma unroll
      for (int n = 0; n < 4; ++n) {
        acc[m][n] = __builtin_amdgcn_mfma_f32_16x16x32_fp8_fp8(a[m][0], b[n][0], acc[m][n], 0, 0, 0);
        acc[m][n] = __builtin_amdgcn_mfma_f32_16x16x32_fp8_fp8(a[m][1], b[n][1], acc[m][n], 0, 0, 0);
      }
    __builtin_amdgcn_s_setprio(0);
  };

  stage(0); stage(1); stage(2);          // 24 issues in flight
  #pragma unroll 1
  for (int kt = 0; kt < 6; ++kt) {
    const int p = 2 * kt;
    WAITVM(16);                          // phase p done (oldest 8 of 24)
    __builtin_amdgcn_s_barrier();
    frags(p);
    WAITLGKM;
    __builtin_amdgcn_s_barrier();        // buffer p%3 free for all waves
    stage(p + 3);
    mmaInto(accK);
    WAITVM(16);                          // phase p+1 done
    __builtin_amdgcn_s_barrier();
    frags(p + 1);
    WAITLGKM;
    __builtin_amdgcn_s_barrier();
    stage(p + 4);
    mmaInto(accL);
  }
  // kt=6: phases 12,13 (stage 15 on X side only)
  WAITVM(16);
  __builtin_amdgcn_s_barrier();
  frags(12);
  WAITLGKM;
  __builtin_amdgcn_s_barrier();
  stage(15);
  mmaInto(accK);
  WAITVM(16);
  __builtin_amdgcn_s_barrier();
  frags(13);
  WAITLGKM;
  mmaInto(accL);
  // kt=7: phases 14,15 (no staging; no buffer overwrites -> single barrier)
  WAITVM(8);
  __builtin_amdgcn_s_barrier();
  frags(14);
  WAITLGKM;
  mmaInto(accK);
  WAITVM(0);
  __builtin_amdgcn_s_barrier();
  frags(15);
  WAITLGKM;
  mmaInto(accL);

  // Epilogue: K = exp(-0.5*max(sq_i + sq_j - 2*G, 0)); off-diag tiles weight 2
  // and contribute column sums.
  float sxj[4], syj[4];
  #pragma unroll
  for (int n = 0; n < 4; ++n) {
    const int j = jb + wc * 64 + n * 16 + fr;
    sxj[n] = sqX[j];
    syj[n] = sqY[j];
  }
  float kl = 0.f;
  float ckK[4] = {0.f, 0.f, 0.f, 0.f}, ckL[4] = {0.f, 0.f, 0.f, 0.f};
  #pragma unroll
  for (int m = 0; m < 4; ++m) {
    #pragma unroll
    for (int r = 0; r < 4; ++r) {
      const int i = ib + wr * 64 + m * 16 + fq * 4 + r;
      const float sxi = sqX[i], syi = sqY[i];
      float rk = 0.f, rl = 0.f;
      #pragma unroll
      for (int n = 0; n < 4; ++n) {
        float dK = fmaxf(sxi + sxj[n] - 2.f * accK[m][n][r], 0.f);
        float Kv = __expf(-0.5f * dK);
        float dL = fmaxf(syi + syj[n] - 2.f * accL[m][n][r], 0.f);
        float Lv = __expf(-0.5f * dL);
        kl += Kv * Lv;
        rk += Kv; rl += Lv;
        ckK[n] += Kv; ckL[n] += Lv;
      }
      #pragma unroll
      for (int msk = 1; msk < 16; msk <<= 1) {
        rk += __shfl_xor(rk, msk);
        rl += __shfl_xor(rl, msk);
      }
      if (fr == 0) {
        atomicAdd(&rowK[i], rk);
        atomicAdd(&rowL[i], rl);
      }
    }
  }
  if (!diag) {
    #pragma unroll
    for (int n = 0; n < 4; ++n) {
      float a2 = ckK[n], b2 = ckL[n];
      a2 += __shfl_xor(a2, 16); a2 += __shfl_xor(a2, 32);
      b2 += __shfl_xor(b2, 16); b2 += __shfl_xor(b2, 32);
      if (fq == 0) {
        const int j = jb + wc * 64 + n * 16 + fr;
        atomicAdd(&rowK[j], a2);
        atomicAdd(&rowL[j], b2);
      }
    }
    kl *= 2.f;
  }
  #pragma unroll
  for (int msk = 1; msk < 64; msk <<= 1) kl += __shfl_xor(kl, msk);
  __shared__ float klred[4];
  if (lane == 0) klred[wave] = kl;
  __syncthreads();
  if (t == 0) atomicAdd(sums, klred[0] + klred[1] + klred[2] + klred[3]);
}

__global__ __launch_bounds__(256) void finalize_kernel(
    const float* __restrict__ rowK, const float* __restrict__ rowL,
    const float* __restrict__ sums, float* __restrict__ out) {
  const int t = threadIdx.x;
  float dp = 0.f, sk = 0.f, sl = 0.f;
  for (int i = t; i < N; i += 256) {
    float a = rowK[i], b = rowL[i];
    dp += a * b; sk += a; sl += b;
  }
  #pragma unroll
  for (int msk = 1; msk < 64; msk <<= 1) {
    dp += __shfl_xor(dp, msk);
    sk += __shfl_xor(sk, msk);
    sl += __shfl_xor(sl, msk);
  }
  __shared__ float r[3][4];
  const int wave = t >> 6, lane = t & 63;
  if (lane == 0) { r[0][wave] = dp; r[1][wave] = sk; r[2][wave] = sl; }
  __syncthreads();
  if (t == 0) {
    float DP = r[0][0] + r[0][1] + r[0][2] + r[0][3];
    float SK = r[1][0] + r[1][1] + r[1][2] + r[1][3];
    float SL = r[2][0] + r[2][1] + r[2][2] + r[2][3];
    const float n = (float)N;
    float raw = sums[0] - (2.f / n) * DP + (SK / n) * (SL / n);
    out[0] = raw / ((n - 1.f) * (n - 1.f));
  }
}

extern "C" void kernel_launch(void* const* d_in, const int* in_sizes, int n_in,
                              void* d_out, int out_size, void* d_ws, size_t ws_size,
                              hipStream_t stream) {
  const float* X = (const float*)d_in[0];
  const float* Y = (const float*)d_in[1];
  char* ws = (char*)d_ws;
  unsigned char* Xb = (unsigned char*)ws;                    // 4 MB
  unsigned char* Yb = (unsigned char*)(ws + (size_t)N * D);  // 4 MB
  float* sqX = (float*)(ws + (size_t)2 * N * D);
  float* sqY = sqX + N;
  float* rowK = sqY + N;
  float* rowL = rowK + N;
  float* sums = rowL + N;

  hipMemsetAsync(rowK, 0, (size_t)(2 * N + 16) * sizeof(float), stream);
  prep_kernel<<<2 * N, 128, 0, stream>>>(X, Y, Xb, Yb, sqX, sqY);
  const int ntiles = (N / 128) * (N / 128 + 1) / 2;  // 2080 triangle tiles
  hsic_main<<<ntiles, 256, 0, stream>>>(Xb, Yb, sqX, sqY, rowK, rowL, sums);
  finalize_kernel<<<1, 256, 0, stream>>>(rowK, rowL, sums, (float*)d_out);
}

// Round 15
// 150.635 us; speedup vs baseline: 1.0779x; 1.0779x over previous
//
#include <hip/hip_runtime.h>
#include <hip/hip_bf16.h>

#define N 8192
#define D 512

typedef __attribute__((ext_vector_type(4))) float f32x4;
typedef __attribute__((ext_vector_type(2))) long i64x2;

#define WAITVM(n) asm volatile("s_waitcnt vmcnt(" #n ")" ::: "memory")
#define BAR __builtin_amdgcn_s_barrier()

__device__ __forceinline__ void g2l16(const void* g, void* l) {
  __builtin_amdgcn_global_load_lds(
      (const __attribute__((address_space(1))) void*)g,
      (__attribute__((address_space(3))) void*)l, 16, 0, 0);
}

// Prep: f32 -> fp8 e4m3, k-permuted per 64-col group (16B chunk j holds
// k{8j..8j+7} | k{32+8j..32+8j+7}) so one b128 read feeds both K=32 halves
// of an MFMA pair. sq from DEQUANTIZED values (diagonal d2 exactly 0).
__global__ __launch_bounds__(128) void prep_kernel(
    const float* __restrict__ X, const float* __restrict__ Y,
    unsigned char* __restrict__ Xb, unsigned char* __restrict__ Yb,
    float* __restrict__ sqX, float* __restrict__ sqY) {
  const int b = blockIdx.x;
  const int row = b & (N - 1);
  const float* src = (b < N) ? X : Y;
  unsigned char* dst = (b < N) ? Xb : Yb;
  float* sq = (b < N) ? sqX : sqY;
  const int t = threadIdx.x;                 // 128 threads x 4 floats = 512
  float4 v = reinterpret_cast<const float4*>(src + (size_t)row * D)[t];
  unsigned p = __builtin_amdgcn_cvt_pk_fp8_f32(v.x, v.y, 0, false);
  p = __builtin_amdgcn_cvt_pk_fp8_f32(v.z, v.w, p, true);
  float f0 = __builtin_amdgcn_cvt_f32_fp8(p, 0);
  float f1 = __builtin_amdgcn_cvt_f32_fp8(p, 1);
  float f2 = __builtin_amdgcn_cvt_f32_fp8(p, 2);
  float f3 = __builtin_amdgcn_cvt_f32_fp8(p, 3);
  float s = f0 * f0 + f1 * f1 + f2 * f2 + f3 * f3;
  const int g = t >> 4;                      // 64-col group
  const int kl = (t & 15) * 4;               // k within group
  const int dest = g * 64 + ((kl & 31) >> 3) * 16 + (kl >> 5) * 8 + (kl & 7);
  *reinterpret_cast<unsigned*>(dst + (size_t)row * D + dest) = p;
  #pragma unroll
  for (int msk = 1; msk < 64; msk <<= 1) s += __shfl_xor(s, msk);
  __shared__ float red[2];
  if ((t & 63) == 0) red[t >> 6] = s;
  __syncthreads();
  if (t == 0) sq[row] = red[0] + red[1];
}

// Fused dual-GEMM (fp8) + RBF + reductions, upper-triangle tiles.
// 8 FAT PHASES (4 kt x {X,Y}), BK=128: halves barrier-convoy count vs R13.
// 2-buffer rotation (X->buf0, Y->buf1), counted vmcnt(8), tail 8->0.
__global__ __launch_bounds__(256, 2) void hsic_main(
    const unsigned char* __restrict__ Xb, const unsigned char* __restrict__ Yb,
    const float* __restrict__ sqX, const float* __restrict__ sqY,
    float* __restrict__ rowK, float* __restrict__ rowL,
    float* __restrict__ sums) {
  __shared__ __align__(16) unsigned char sbuf[2][2][128 * 128];  // 64 KB

  const int bid = (blockIdx.x & 7) * 260 + (blockIdx.x >> 3);  // XCD chunks
  int ti = (int)((129.0f - sqrtf(16641.0f - 8.0f * (float)bid)) * 0.5f);
  while (ti > 0 && (ti * (129 - ti)) / 2 > bid) --ti;
  while (((ti + 1) * (128 - ti)) / 2 <= bid) ++ti;
  const int tj = ti + (bid - (ti * (129 - ti)) / 2);
  const bool diag = (ti == tj);

  const int ib = ti * 128, jb = tj * 128;
  const int t = threadIdx.x;
  const int lane = t & 63, wave = t >> 6;
  const int wr = wave >> 1, wc = wave & 1;     // 2x2 waves, 64x64 tiles
  const int fr = lane & 15, fq = lane >> 4;

  f32x4 accK[4][4], accL[4][4];
  #pragma unroll
  for (int m = 0; m < 4; ++m)
    #pragma unroll
    for (int n = 0; n < 4; ++n) { accK[m][n] = (f32x4)0.f; accL[m][n] = (f32x4)0.f; }

  const unsigned char* s0 = Xb + (size_t)ib * D;
  const unsigned char* s1 = Xb + (size_t)jb * D;
  const unsigned char* s2 = Yb + (size_t)ib * D;
  const unsigned char* s3 = Yb + (size_t)jb * D;

  // Stage: 256 threads x 16B = 4KB = 32 rows x 128B per issue; 4 issues/panel.
  // row = q*32 + t/8, chunk = t&7; source pre-swizzled by (row&7)<<4
  // (row&7 = (t>>3)&7, q-independent since q*32 keeps bits 0-2 of row).
  const int srow = t >> 3;
  const int swcb = ((t & 7) * 16) ^ (((t >> 3) & 7) << 4);
  const int lo16 = t * 16;

  // 8 vmem issues per phase-stage (4 per panel).
  auto stage = [&](int ph) {
    const int kt = ph >> 1;
    const unsigned char* si = (ph & 1) ? s2 : s0;
    const unsigned char* sj = (ph & 1) ? s3 : s1;
    unsigned char* di = sbuf[ph & 1][0];
    unsigned char* dj = sbuf[ph & 1][1];
    #pragma unroll
    for (int q = 0; q < 4; ++q) {
      const size_t goff = (size_t)(q * 32 + srow) * D + kt * 128 + swcb;
      const int lo = q * 4096 + lo16;
      g2l16(si + goff, di + lo);
      g2l16(sj + goff, dj + lo);
    }
  };

  // One fat phase: 2 kk-subgroups of {8 ds_read_b128 + 16 MFMA}.
  auto compute = [&](const unsigned char* si, const unsigned char* sj,
                     f32x4 (&acc)[4][4]) {
    #pragma unroll
    for (int kk = 0; kk < 2; ++kk) {
      const int csel = kk * 64 + fq * 16;          // chunk col within row
      i64x2 a[4], b[4];
      #pragma unroll
      for (int m = 0; m < 4; ++m) {
        const int row = wr * 64 + m * 16 + fr;
        a[m] = *(const i64x2*)&si[row * 128 + (csel ^ ((fr & 7) << 4))];
      }
      #pragma unroll
      for (int n = 0; n < 4; ++n) {
        const int row = wc * 64 + n * 16 + fr;
        b[n] = *(const i64x2*)&sj[row * 128 + (csel ^ ((fr & 7) << 4))];
      }
      __builtin_amdgcn_s_setprio(1);
      #pragma unroll
      for (int m = 0; m < 4; ++m)
        #pragma unroll
        for (int n = 0; n < 4; ++n) {
          acc[m][n] = __builtin_amdgcn_mfma_f32_16x16x32_fp8_fp8(a[m][0], b[n][0], acc[m][n], 0, 0, 0);
          acc[m][n] = __builtin_amdgcn_mfma_f32_16x16x32_fp8_fp8(a[m][1], b[n][1], acc[m][n], 0, 0, 0);
        }
      __builtin_amdgcn_s_setprio(0);
    }
  };

  stage(0); stage(1);                    // 16 issues in flight
  #pragma unroll 1
  for (int kt = 0; kt < 3; ++kt) {
    // X phase (buf0): own stage is oldest 8 of 16
    WAITVM(8);
    BAR;
    compute(sbuf[0][0], sbuf[0][1], accK);
    BAR;                                 // buf0 free for all waves
    stage(2 * kt + 2);
    // Y phase (buf1)
    WAITVM(8);
    BAR;
    compute(sbuf[1][0], sbuf[1][1], accL);
    BAR;
    stage(2 * kt + 3);
  }
  // kt=3: phases 6,7 — no further staging
  WAITVM(8);                             // stage(6) done, stage(7) in flight
  BAR;
  compute(sbuf[0][0], sbuf[0][1], accK);
  WAITVM(0);                             // stage(7) done
  BAR;
  compute(sbuf[1][0], sbuf[1][1], accL);

  // Epilogue: K = exp(-0.5*max(sq_i + sq_j - 2*G, 0)); off-diag tiles weight 2
  // and contribute column sums.
  float sxj[4], syj[4];
  #pragma unroll
  for (int n = 0; n < 4; ++n) {
    const int j = jb + wc * 64 + n * 16 + fr;
    sxj[n] = sqX[j];
    syj[n] = sqY[j];
  }
  float kl = 0.f;
  float ckK[4] = {0.f, 0.f, 0.f, 0.f}, ckL[4] = {0.f, 0.f, 0.f, 0.f};
  #pragma unroll
  for (int m = 0; m < 4; ++m) {
    #pragma unroll
    for (int r = 0; r < 4; ++r) {
      const int i = ib + wr * 64 + m * 16 + fq * 4 + r;
      const float sxi = sqX[i], syi = sqY[i];
      float rk = 0.f, rl = 0.f;
      #pragma unroll
      for (int n = 0; n < 4; ++n) {
        float dK = fmaxf(sxi + sxj[n] - 2.f * accK[m][n][r], 0.f);
        float Kv = __expf(-0.5f * dK);
        float dL = fmaxf(syi + syj[n] - 2.f * accL[m][n][r], 0.f);
        float Lv = __expf(-0.5f * dL);
        kl += Kv * Lv;
        rk += Kv; rl += Lv;
        ckK[n] += Kv; ckL[n] += Lv;
      }
      #pragma unroll
      for (int msk = 1; msk < 16; msk <<= 1) {
        rk += __shfl_xor(rk, msk);
        rl += __shfl_xor(rl, msk);
      }
      if (fr == 0) {
        atomicAdd(&rowK[i], rk);
        atomicAdd(&rowL[i], rl);
      }
    }
  }
  if (!diag) {
    #pragma unroll
    for (int n = 0; n < 4; ++n) {
      float a2 = ckK[n], b2 = ckL[n];
      a2 += __shfl_xor(a2, 16); a2 += __shfl_xor(a2, 32);
      b2 += __shfl_xor(b2, 16); b2 += __shfl_xor(b2, 32);
      if (fq == 0) {
        const int j = jb + wc * 64 + n * 16 + fr;
        atomicAdd(&rowK[j], a2);
        atomicAdd(&rowL[j], b2);
      }
    }
    kl *= 2.f;
  }
  #pragma unroll
  for (int msk = 1; msk < 64; msk <<= 1) kl += __shfl_xor(kl, msk);
  __shared__ float klred[4];
  if (lane == 0) klred[wave] = kl;
  __syncthreads();
  if (t == 0) atomicAdd(sums, klred[0] + klred[1] + klred[2] + klred[3]);
}

__global__ __launch_bounds__(256) void finalize_kernel(
    const float* __restrict__ rowK, const float* __restrict__ rowL,
    const float* __restrict__ sums, float* __restrict__ out) {
  const int t = threadIdx.x;
  float dp = 0.f, sk = 0.f, sl = 0.f;
  for (int i = t; i < N; i += 256) {
    float a = rowK[i], b = rowL[i];
    dp += a * b; sk += a; sl += b;
  }
  #pragma unroll
  for (int msk = 1; msk < 64; msk <<= 1) {
    dp += __shfl_xor(dp, msk);
    sk += __shfl_xor(sk, msk);
    sl += __shfl_xor(sl, msk);
  }
  __shared__ float r[3][4];
  const int wave = t >> 6, lane = t & 63;
  if (lane == 0) { r[0][wave] = dp; r[1][wave] = sk; r[2][wave] = sl; }
  __syncthreads();
  if (t == 0) {
    float DP = r[0][0] + r[0][1] + r[0][2] + r[0][3];
    float SK = r[1][0] + r[1][1] + r[1][2] + r[1][3];
    float SL = r[2][0] + r[2][1] + r[2][2] + r[2][3];
    const float n = (float)N;
    float raw = sums[0] - (2.f / n) * DP + (SK / n) * (SL / n);
    out[0] = raw / ((n - 1.f) * (n - 1.f));
  }
}

extern "C" void kernel_launch(void* const* d_in, const int* in_sizes, int n_in,
                              void* d_out, int out_size, void* d_ws, size_t ws_size,
                              hipStream_t stream) {
  const float* X = (const float*)d_in[0];
  const float* Y = (const float*)d_in[1];
  char* ws = (char*)d_ws;
  unsigned char* Xb = (unsigned char*)ws;                    // 4 MB
  unsigned char* Yb = (unsigned char*)(ws + (size_t)N * D);  // 4 MB
  float* sqX = (float*)(ws + (size_t)2 * N * D);
  float* sqY = sqX + N;
  float* rowK = sqY + N;
  float* rowL = rowK + N;
  float* sums = rowL + N;

  hipMemsetAsync(rowK, 0, (size_t)(2 * N + 16) * sizeof(float), stream);
  prep_kernel<<<2 * N, 128, 0, stream>>>(X, Y, Xb, Yb, sqX, sqY);
  const int ntiles = (N / 128) * (N / 128 + 1) / 2;  // 2080 triangle tiles
  hsic_main<<<ntiles, 256, 0, stream>>>(Xb, Yb, sqX, sqY, rowK, rowL, sums);
  finalize_kernel<<<1, 256, 0, stream>>>(rowK, rowL, sums, (float*)d_out);
}